// Round 4
// baseline (87.427 us; speedup 1.0000x reference)
//
#include <hip/hip_runtime.h>

#define NTHREADS 512
#define N_FEAT   8192
#define NB0      4096                 // 12-bit first digit
#define SKSZ     (NB0 + NB0 / 8)      // skewed size: 4608 = 9*512
#define CAP      2048                 // candidate buffer capacity
#define ROWS     4                    // rows per block (software pipeline)

typedef float f4v __attribute__((ext_vector_type(4)));

// float -> order-preserving unsigned key (exact bijection)
__device__ __forceinline__ unsigned f2k(float f) {
    unsigned u = __float_as_uint(f);
    return u ^ (unsigned)(((int)u >> 31) | 0x80000000);
}
__device__ __forceinline__ float k2f(unsigned kk) {
    return __uint_as_float(kk ^ (unsigned)(((int)(~kk) >> 31) | 0x80000000));
}

__global__ __launch_bounds__(NTHREADS) void ksparse_kernel(
    const float* __restrict__ x, const int* __restrict__ kptr,
    float* __restrict__ out, int nrows) {

    const int t    = threadIdx.x;
    const int lane = t & 63;
    const int w    = t >> 6;

    __shared__ unsigned hist[SKSZ];    // skewed: phys(b) = b + (b>>3)
    __shared__ unsigned cand[CAP];
    __shared__ unsigned ws[8];
    __shared__ unsigned s_bucket, s_r, s_kth;
    __shared__ unsigned s_cnt[2];      // ping-pong gather counter

    const int row0 = blockIdx.x * ROWS;
    const size_t rowbase = (size_t)row0 * N_FEAT;
    const f4v* xv = (const f4v*)(x + rowbase);
    f4v* ov = (f4v*)(out + rowbase);

    // issue row-0 loads; clear overlaps their latency
    f4v c0 = xv[t], c1 = xv[t + 512], c2 = xv[t + 1024], c3 = xv[t + 1536];

#pragma unroll
    for (int i = 0; i < SKSZ / NTHREADS; ++i) hist[t + i * NTHREADS] = 0u;
    if (t == 0) { s_cnt[0] = 0u; s_cnt[1] = 0u; }
    __syncthreads();

    const unsigned r = (unsigned)kptr[0] + 1u;   // (k+1)-th largest

    for (int rr = 0; rr < ROWS; ++rr) {
        if (row0 + rr >= nrows) break;           // block-uniform
        const int p = rr & 1;

        // ---- prefetch next row (in flight across all compute phases) ----
        f4v n0, n1, n2, n3;
        if (rr + 1 < ROWS && row0 + rr + 1 < nrows) {
            const f4v* nv = xv + (size_t)(rr + 1) * (N_FEAT / 4);
            n0 = nv[t]; n1 = nv[t + 512]; n2 = nv[t + 1024]; n3 = nv[t + 1536];
        }

        // ---- 12-bit histogram (skewed addressing) ----
        {
            auto h4 = [&](f4v v) {
#pragma unroll
                for (int j = 0; j < 4; ++j) {
                    unsigned b = f2k(v[j]) >> 20;
                    atomicAdd(&hist[b + (b >> 3)], 1u);
                }
            };
            h4(c0); h4(c1); h4(c2); h4(c3);
        }
        __syncthreads();                         // B2

        // ---- all-thread suffix scan: thread t owns buckets [8t, 8t+8) ----
        unsigned h[8], sum8 = 0;
#pragma unroll
        for (int j = 0; j < 8; ++j) { h[j] = hist[9 * t + j]; sum8 += h[j]; }
        unsigned S = sum8;
#pragma unroll
        for (int off = 1; off < 64; off <<= 1) {
            unsigned q = (unsigned)__shfl_down((int)S, off, 64);
            if (lane + off < 64) S += q;
        }
        if (lane == 0) ws[w] = S;
        __syncthreads();                         // B3
        unsigned above = S - sum8;
#pragma unroll
        for (int w2 = 1; w2 < 8; ++w2) if (w2 > w) above += ws[w2];
        if (above < r && above + sum8 >= r) {    // exactly one thread
            unsigned acc = above;
#pragma unroll
            for (int j = 7; j >= 0; --j) {
                if (acc < r && acc + h[j] >= r) { s_bucket = (unsigned)(8 * t + j); s_r = r - acc; }
                acc += h[j];
            }
        }
        __syncthreads();                         // B4
        const unsigned bucket = s_bucket;
        const unsigned r2 = s_r;

        // ---- gather candidates; clear hist for next row in same interval ----
        {
            auto g4 = [&](f4v v) {
#pragma unroll
                for (int j = 0; j < 4; ++j) {
                    unsigned kk = f2k(v[j]);
                    if ((kk >> 20) == bucket) {
                        unsigned q = atomicAdd(&s_cnt[p], 1u);
                        if (q < CAP) cand[q] = kk;
                    }
                }
            };
            g4(c0); g4(c1); g4(c2); g4(c3);
        }
#pragma unroll
        for (int i = 0; i < SKSZ / NTHREADS; ++i) hist[t + i * NTHREADS] = 0u;
        if (t == 0) s_cnt[p ^ 1] = 0u;
        __syncthreads();                         // B5
        const unsigned m = s_cnt[p];

        if (m <= CAP) {
            // exact rank via pairwise count (cand[j2] reads are LDS broadcasts)
            for (unsigned i = t; i < m; i += NTHREADS) {
                unsigned ki = cand[i], g = 0, ge = 0;
                for (unsigned j2 = 0; j2 < m; ++j2) {
                    unsigned kj = cand[j2];
                    g  += (kj > ki);
                    ge += (kj >= ki);
                }
                if (g < r2 && ge >= r2) s_kth = ki;   // unique value
            }
        } else {
            // adversarial-only fallback: two 10-bit radix passes (hist[0..1023] zero here)
            unsigned prefix = bucket << 20, rk = r2;
            for (int pass = 0; pass < 2; ++pass) {
                const int shift = pass == 0 ? 10 : 0;
                const unsigned hm = pass == 0 ? 0xFFF00000u : 0xFFFFFC00u;
                auto a4 = [&](f4v v) {
#pragma unroll
                    for (int j = 0; j < 4; ++j) {
                        unsigned kk = f2k(v[j]);
                        if ((kk & hm) == prefix) atomicAdd(&hist[(kk >> shift) & 1023u], 1u);
                    }
                };
                a4(c0); a4(c1); a4(c2); a4(c3);
                __syncthreads();
                if (t < 64) {
                    unsigned C = 0, hh[16];
#pragma unroll
                    for (int j2 = 0; j2 < 16; ++j2) { hh[j2] = hist[t * 16 + j2]; C += hh[j2]; }
                    unsigned S2 = C;
#pragma unroll
                    for (int off = 1; off < 64; off <<= 1) {
                        unsigned q = (unsigned)__shfl_down((int)S2, off, 64);
                        if (lane + off < 64) S2 += q;
                    }
                    unsigned carry = S2 - C;
                    if (S2 >= rk && carry < rk) {
                        unsigned acc = carry;
#pragma unroll
                        for (int j2 = 15; j2 >= 0; --j2) {
                            if (acc < rk && acc + hh[j2] >= rk) { s_bucket = (unsigned)(t * 16 + j2); s_r = rk - acc; }
                            acc += hh[j2];
                        }
                    }
                }
                __syncthreads();
                prefix |= s_bucket << shift;
                rk = s_r;
                hist[t] = 0u; hist[t + 512] = 0u;    // restore zeros
                __syncthreads();
            }
            if (t == 0) s_kth = prefix;
        }
        __syncthreads();                         // B6
        const float kthf = k2f(s_kth);

        // ---- masked write: float compare == reference semantics exactly ----
        f4v* orow = ov + (size_t)rr * (N_FEAT / 4);
        {
            auto w4 = [&](f4v v, int idx) {
                f4v o;
#pragma unroll
                for (int j = 0; j < 4; ++j) o[j] = (v[j] > kthf) ? v[j] : 0.0f;
                __builtin_nontemporal_store(o, orow + idx);
            };
            w4(c0, t); w4(c1, t + 512); w4(c2, t + 1024); w4(c3, t + 1536);
        }

        c0 = n0; c1 = n1; c2 = n2; c3 = n3;      // rotate pipeline
    }
}

extern "C" void kernel_launch(void* const* d_in, const int* in_sizes, int n_in,
                              void* d_out, int out_size, void* d_ws, size_t ws_size,
                              hipStream_t stream) {
    const float* x = (const float*)d_in[0];
    const int* k   = (const int*)d_in[1];
    float* out     = (float*)d_out;
    const int B = in_sizes[0] / N_FEAT;
    const int grid = (B + ROWS - 1) / ROWS;
    ksparse_kernel<<<grid, NTHREADS, 0, stream>>>(x, k, out, B);
}

// Round 5
// 53.801 us; speedup vs baseline: 1.6250x; 1.6250x over previous
//
#include <hip/hip_runtime.h>

#define NTHREADS 512
#define N_FEAT   8192
#define NB0      4096                 // 12-bit first digit
#define SKSZ     (NB0 + NB0 / 8)      // skewed: phys(b) = b + (b>>3), size 4608
#define CAP      2048                 // candidate buffer capacity

typedef float f4v __attribute__((ext_vector_type(4)));

// float -> order-preserving unsigned key (exact bijection)
__device__ __forceinline__ unsigned f2k(float f) {
    unsigned u = __float_as_uint(f);
    return u ^ (unsigned)(((int)u >> 31) | 0x80000000);
}
__device__ __forceinline__ float k2f(unsigned kk) {
    return __uint_as_float(kk ^ (unsigned)(((int)(~kk) >> 31) | 0x80000000));
}

__global__ __launch_bounds__(NTHREADS) void ksparse_kernel(
    const float* __restrict__ x, const int* __restrict__ kptr,
    float* __restrict__ out) {

    const int t    = threadIdx.x;
    const int lane = t & 63;
    const int w    = t >> 6;
    const size_t base = (size_t)blockIdx.x * N_FEAT;

    __shared__ unsigned hist[SKSZ];
    __shared__ unsigned cand[CAP];
    __shared__ unsigned ws[8];
    __shared__ unsigned s_bucket, s_r, s_cnt, s_kth;

    // issue row loads; histogram clear overlaps their latency
    const f4v* xv = (const f4v*)(x + base);
    f4v c0 = xv[t], c1 = xv[t + 512], c2 = xv[t + 1024], c3 = xv[t + 1536];

#pragma unroll
    for (int i = 0; i < SKSZ / NTHREADS; ++i) hist[t + i * NTHREADS] = 0u;
    if (t == 0) s_cnt = 0u;
    __syncthreads();                                 // B1

    const unsigned r = (unsigned)kptr[0] + 1u;       // (k+1)-th largest

    // ---- 12-bit histogram (skewed: adjacent buckets -> adjacent banks) ----
    {
        auto h4 = [&](f4v v) {
#pragma unroll
            for (int j = 0; j < 4; ++j) {
                unsigned b = f2k(v[j]) >> 20;
                atomicAdd(&hist[b + (b >> 3)], 1u);
            }
        };
        h4(c0); h4(c1); h4(c2); h4(c3);
    }
    __syncthreads();                                 // B2

    // ---- all-thread suffix scan: thread t owns buckets [8t, 8t+8) ----
    // phys(8t+j) = 9t + j  (lane stride 9, gcd(9,32)=1 -> conflict-free)
    unsigned h[8], sum8 = 0;
#pragma unroll
    for (int j = 0; j < 8; ++j) { h[j] = hist[9 * t + j]; sum8 += h[j]; }
    unsigned S = sum8;
#pragma unroll
    for (int off = 1; off < 64; off <<= 1) {
        unsigned q = (unsigned)__shfl_down((int)S, off, 64);
        if (lane + off < 64) S += q;
    }
    if (lane == 0) ws[w] = S;
    __syncthreads();                                 // B3
    unsigned above = S - sum8;
#pragma unroll
    for (int w2 = 1; w2 < 8; ++w2) if (w2 > w) above += ws[w2];
    if (above < r && above + sum8 >= r) {            // exactly one thread
        unsigned acc = above;
#pragma unroll
        for (int j = 7; j >= 0; --j) {
            if (acc < r && acc + h[j] >= r) { s_bucket = (unsigned)(8 * t + j); s_r = r - acc; }
            acc += h[j];
        }
    }
    __syncthreads();                                 // B4
    const unsigned bucket = s_bucket;
    const unsigned r2 = s_r;

    // ---- gather the bucket's candidates (typ. ~130 of 8192) ----
    {
        auto g4 = [&](f4v v) {
#pragma unroll
            for (int j = 0; j < 4; ++j) {
                unsigned kk = f2k(v[j]);
                if ((kk >> 20) == bucket) {
                    unsigned q = atomicAdd(&s_cnt, 1u);
                    if (q < CAP) cand[q] = kk;
                }
            }
        };
        g4(c0); g4(c1); g4(c2); g4(c3);
    }
    __syncthreads();                                 // B5
    const unsigned m = s_cnt;

    if (m <= CAP) {
        // exact rank via pairwise count (cand[j2] reads broadcast, conflict-free)
        for (unsigned i = t; i < m; i += NTHREADS) {
            unsigned ki = cand[i], g = 0, ge = 0;
            for (unsigned j2 = 0; j2 < m; ++j2) {
                unsigned kj = cand[j2];
                g  += (kj > ki);
                ge += (kj >= ki);
            }
            if (g < r2 && ge >= r2) s_kth = ki;      // unique value, race-safe
        }
    } else {
        // adversarial-only fallback: two 10-bit radix passes
        unsigned prefix = bucket << 20, rk = r2;
        for (int pass = 0; pass < 2; ++pass) {
            const int shift = pass == 0 ? 10 : 0;
            const unsigned hm = pass == 0 ? 0xFFF00000u : 0xFFFFFC00u;
            hist[t] = 0u; hist[t + 512] = 0u;
            __syncthreads();
            auto a4 = [&](f4v v) {
#pragma unroll
                for (int j = 0; j < 4; ++j) {
                    unsigned kk = f2k(v[j]);
                    if ((kk & hm) == prefix) atomicAdd(&hist[(kk >> shift) & 1023u], 1u);
                }
            };
            a4(c0); a4(c1); a4(c2); a4(c3);
            __syncthreads();
            if (t < 64) {
                unsigned C = 0, hh[16];
#pragma unroll
                for (int j2 = 0; j2 < 16; ++j2) { hh[j2] = hist[t * 16 + j2]; C += hh[j2]; }
                unsigned S2 = C;
#pragma unroll
                for (int off = 1; off < 64; off <<= 1) {
                    unsigned q = (unsigned)__shfl_down((int)S2, off, 64);
                    if (lane + off < 64) S2 += q;
                }
                unsigned carry = S2 - C;
                if (S2 >= rk && carry < rk) {
                    unsigned acc = carry;
#pragma unroll
                    for (int j2 = 15; j2 >= 0; --j2) {
                        if (acc < rk && acc + hh[j2] >= rk) { s_bucket = (unsigned)(t * 16 + j2); s_r = rk - acc; }
                        acc += hh[j2];
                    }
                }
            }
            __syncthreads();
            prefix |= s_bucket << shift;
            rk = s_r;
        }
        if (t == 0) s_kth = prefix;
    }
    __syncthreads();                                 // B6
    const float kthf = k2f(s_kth);

    // ---- masked write: float compare == reference semantics exactly ----
    f4v* ov = (f4v*)(out + base);
    {
        auto w4 = [&](f4v v, int idx) {
            f4v o;
#pragma unroll
            for (int j = 0; j < 4; ++j) o[j] = (v[j] > kthf) ? v[j] : 0.0f;
            __builtin_nontemporal_store(o, ov + idx);
        };
        w4(c0, t); w4(c1, t + 512); w4(c2, t + 1024); w4(c3, t + 1536);
    }
}

extern "C" void kernel_launch(void* const* d_in, const int* in_sizes, int n_in,
                              void* d_out, int out_size, void* d_ws, size_t ws_size,
                              hipStream_t stream) {
    const float* x = (const float*)d_in[0];
    const int* k   = (const int*)d_in[1];
    float* out     = (float*)d_out;
    const int B = in_sizes[0] / N_FEAT;
    ksparse_kernel<<<B, NTHREADS, 0, stream>>>(x, k, out);
}